// Round 10
// baseline (124.223 us; speedup 1.0000x reference)
//
#include <hip/hip_runtime.h>
#include <math.h>

#define N      512
#define RNUM   4
#define BNUM   2
#define NSLICE (RNUM * BNUM)
#define TILE   128               // (a,b) tile 128x128, 256 threads x (8x8)
#define CT     32                // c-chunk per LDS stage (f16 tiles)
#define LSTR   136               // f16 row stride (272 B) - bank-verified
#define CSPLIT 8                 // c-split: 2 chunks/block -> 1024 main blocks
#define NCOLB  16                // colsum-role blocks (8 slices x 2 halves)
#define SCALE  0.0625f           // (1/2 relu-split) * (1/8 weight/(R*B))

typedef _Float16 half2_t __attribute__((ext_vector_type(2)));

__device__ __forceinline__ unsigned int h2u(half2_t h) {
  return __builtin_bit_cast(unsigned int, h);
}
__device__ __forceinline__ half2_t u2h(unsigned int u) {
  return __builtin_bit_cast(half2_t, u);
}

__device__ __forceinline__ float sigmoidf_(float x) {
  return 1.0f / (1.0f + __expf(-x));
}

__global__ void zero_out_kernel(float* out) { out[0] = 0.0f; }

// One thread per (b,i,j): reads float4 over r, writes 4 f16 slice planes
// P[s][i][j] (row-major, mask+sigmoid folded). Coalesced 2B stores.
// Block 0 thread 0 zeroes the output accumulator.
__global__ __launch_bounds__(256) void prep_f16_kernel(const float* __restrict__ logits,
                                                       const int* __restrict__ masks,
                                                       _Float16* __restrict__ P,
                                                       float* __restrict__ out) {
  if (blockIdx.x == 0 && threadIdx.x == 0) out[0] = 0.0f;
  int t = blockIdx.x * 256 + threadIdx.x;      // 0 .. B*N*N-1
  int b = t >> 18;                              // / (N*N)
  int rem = t & (N * N - 1);
  int i = rem >> 9;
  int j = rem & (N - 1);
  float4 lg = *(const float4*)(logits + (size_t)t * 4);
  float mm = ((masks[b * N + i] > 0) && (masks[b * N + j] > 0)) ? 1.0f : 0.0f;
  size_t base = (size_t)b * RNUM * N * N + rem;
  P[base + 0 * (size_t)N * N] = (_Float16)(mm * sigmoidf_(lg.x));
  P[base + 1 * (size_t)N * N] = (_Float16)(mm * sigmoidf_(lg.y));
  P[base + 2 * (size_t)N * N] = (_Float16)(mm * sigmoidf_(lg.z));
  P[base + 3 * (size_t)N * N] = (_Float16)(mm * sigmoidf_(lg.w));
}

// Work kernel (f16 path), two roles by blockIdx.x:
//  bid <  NCOLB : colsum role — Sum_c csum_c*(N-csum_c)  (factorized Sum(x))
//  bid >= NCOLB : main role — Sum |rab - a_c*b_c| via packed f16, 3 ops/pair:
//    t2 = v_pk_fma_f16(asp, bv, -rab2)   (sign pre-flipped; |−x|=|x|)
//    p2 = t2 & 0x7FFF7FFF                (packed abs)
//    acc2 += p2                          (v_pk_add_f16; flushed to f32/chunk)
//  f16-acc precision: ≤32 values of ≤1.0 per lane per chunk; rounding noise
//  σ≈65 on a ~1e7 result, threshold 7.3e5 — fine.
// R8 post-mortem: VALU issue was 2x the 3-op model — suspect fdot2 fallback
// or mul+sub split; this version forces fma via __builtin_elementwise_fma
// and drops dot2 entirely.
__global__ __launch_bounds__(256) void work_f16_kernel(const _Float16* __restrict__ P,
                                                       float* __restrict__ out) {
  __shared__ _Float16 tA[CT][LSTR];
  __shared__ _Float16 tB[CT][LSTR];
  __shared__ float wsum[4];

  const int tid = threadIdx.x;
  const int bid = blockIdx.x;

  if (bid < NCOLB) {
    // ---- colsum role ----
    const int s    = bid >> 1;
    const int half = bid & 1;
    const int c    = half * 256 + tid;
    const _Float16* col = P + (size_t)s * N * N + c;
    float sum = 0.0f;
#pragma unroll 8
    for (int a = 0; a < N; ++a) sum += (float)col[(size_t)a * N];
    float v = sum * ((float)N - sum);
    for (int off = 32; off > 0; off >>= 1) v += __shfl_down(v, off, 64);
    const int wid = tid >> 6;
    if ((tid & 63) == 0) wsum[wid] = v;
    __syncthreads();
    if (tid == 0)
      atomicAdd(out, (wsum[0] + wsum[1] + wsum[2] + wsum[3]) * SCALE);
    return;
  }

  // ---- main role ----
  const int m  = bid - NCOLB;
  const int bt = m & 3;
  const int at = (m >> 2) & 3;
  const int s  = (m >> 4) & 7;
  const int cz = m >> 7;                    // 0..CSPLIT-1
  const int a0 = at * TILE;
  const int b0 = bt * TILE;
  const int cbeg = cz * (N / CSPLIT);       // 64-wide c-range = 2 chunks
  const int cend = cbeg + (N / CSPLIT);

  const int ta = tid & 15;    // a cols (tile-local): ta*4+0..3 and 64+ta*4+0..3
  const int tb = tid >> 4;    // b cols (tile-local): tb*4+0..3 and 64+tb*4+0..3

  const _Float16* Ph = P + (size_t)s * N * N;

  // nrab2[x][yp] = -{rab[x][2yp], rab[x][2yp+1]}  (sign flipped at load)
  half2_t nrab2[8][4];
#pragma unroll
  for (int x = 0; x < 8; ++x) {
    int ga = a0 + ((x >> 2) << 6) + ta * 4 + (x & 3);
    uint2 u0 = *(const uint2*)(Ph + (size_t)ga * N + b0 + tb * 4);
    uint2 u1 = *(const uint2*)(Ph + (size_t)ga * N + b0 + 64 + tb * 4);
    nrab2[x][0] = u2h(u0.x ^ 0x80008000u);
    nrab2[x][1] = u2h(u0.y ^ 0x80008000u);
    nrab2[x][2] = u2h(u1.x ^ 0x80008000u);
    nrab2[x][3] = u2h(u1.y ^ 0x80008000u);
  }

  float acc[8];
#pragma unroll
  for (int x = 0; x < 8; ++x) acc[x] = 0.0f;

  // staging role for this thread: one tile row -> LDS column sx
  const int sx   = tid & 127;
  const int sarr = tid >> 7;                // 0 -> A, 1 -> B
  const _Float16* srow = Ph + (size_t)((sarr ? b0 : a0) + sx) * N;
  _Float16* dcol = sarr ? &tB[0][sx] : &tA[0][sx];

  for (int c0 = cbeg; c0 < cend; c0 += CT) {
    __syncthreads();
    {
      // 64 B of c for row sx, transposed into LDS column sx (all 32 rows)
      const uint4* src = (const uint4*)(srow + c0);
      uint4 q0 = src[0];
      uint4 q1 = src[1];
      uint4 q2 = src[2];
      uint4 q3 = src[3];
      unsigned int w[16] = {q0.x, q0.y, q0.z, q0.w, q1.x, q1.y, q1.z, q1.w,
                            q2.x, q2.y, q2.z, q2.w, q3.x, q3.y, q3.z, q3.w};
      union { unsigned int u32; _Float16 h[2]; } cv;
#pragma unroll
      for (int k = 0; k < 16; ++k) {
        cv.u32 = w[k];
        dcol[(size_t)(2 * k) * LSTR]     = cv.h[0];
        dcol[(size_t)(2 * k + 1) * LSTR] = cv.h[1];
      }
    }
    __syncthreads();

    // packed f16 accumulators for this chunk (max 32 adds of <=1.0)
    half2_t acc2[8][4];
#pragma unroll
    for (int x = 0; x < 8; ++x)
#pragma unroll
      for (int yp = 0; yp < 4; ++yp)
        acc2[x][yp] = u2h(0u);

#pragma unroll 4
    for (int c = 0; c < CT; ++c) {
      uint2 ua0 = *(const uint2*)&tA[c][ta * 4];
      uint2 ua1 = *(const uint2*)&tA[c][64 + ta * 4];
      uint2 ub0 = *(const uint2*)&tB[c][tb * 4];
      uint2 ub1 = *(const uint2*)&tB[c][64 + tb * 4];
      half2_t av[4] = {u2h(ua0.x), u2h(ua0.y), u2h(ua1.x), u2h(ua1.y)};
      half2_t bv[4] = {u2h(ub0.x), u2h(ub0.y), u2h(ub1.x), u2h(ub1.y)};
#pragma unroll
      for (int x = 0; x < 8; ++x) {
        _Float16 as = (x & 1) ? av[x >> 1].y : av[x >> 1].x;
        half2_t asp = {as, as};
#pragma unroll
        for (int yp = 0; yp < 4; ++yp) {
          half2_t t2 = __builtin_elementwise_fma(asp, bv[yp], nrab2[x][yp]);
          acc2[x][yp] += u2h(h2u(t2) & 0x7FFF7FFFu);   // pk_add(|t|)
        }
      }
    }

    // flush packed accumulators to f32
#pragma unroll
    for (int x = 0; x < 8; ++x) {
      float fx = acc[x];
#pragma unroll
      for (int yp = 0; yp < 4; ++yp)
        fx += (float)acc2[x][yp].x + (float)acc2[x][yp].y;
      acc[x] = fx;
    }
  }

  float tsum = 0.0f;
#pragma unroll
  for (int x = 0; x < 8; ++x) tsum += acc[x];

  for (int off = 32; off > 0; off >>= 1) tsum += __shfl_down(tsum, off, 64);

  const int wid = tid >> 6;
  if ((tid & 63) == 0) wsum[wid] = tsum;
  __syncthreads();
  if (tid == 0)
    atomicAdd(out, (wsum[0] + wsum[1] + wsum[2] + wsum[3]) * SCALE);
}

// ---------------- f32 fallback (no workspace): R4 structure ----------------
#define FCT    64
#define FSTR   132
#define FCSPL  4

__global__ __launch_bounds__(256, 2) void work_f32_fallback(const float* __restrict__ logits,
                                                            const int* __restrict__ masks,
                                                            float* __restrict__ out) {
  __shared__ __align__(16) float tA[FCT][FSTR];
  __shared__ __align__(16) float tB[FCT][FSTR];
  __shared__ float wsum[4];

  const int tid = threadIdx.x;
  const int bid = blockIdx.x;

  if (bid < NCOLB) {
    const int s    = bid >> 1;
    const int half = bid & 1;
    const int c    = half * 256 + tid;
    const int bb   = s >> 2;
    const int r    = s & 3;
    const int* mrow = masks + bb * N;
    float mc = (mrow[c] > 0) ? 1.0f : 0.0f;
    float sum = 0.0f;
#pragma unroll 4
    for (int a = 0; a < N; ++a) {
      float ma = (mrow[a] > 0) ? 1.0f : 0.0f;
      size_t idx = ((size_t)(bb * N + a) * N + c) * RNUM + r;
      sum += sigmoidf_(logits[idx]) * ma * mc;
    }
    float v = sum * ((float)N - sum);
    for (int off = 32; off > 0; off >>= 1) v += __shfl_down(v, off, 64);
    const int wid = tid >> 6;
    if ((tid & 63) == 0) wsum[wid] = v;
    __syncthreads();
    if (tid == 0)
      atomicAdd(out, (wsum[0] + wsum[1] + wsum[2] + wsum[3]) * SCALE);
    return;
  }

  const int m  = bid - NCOLB;
  const int bt = m & 3;
  const int at = (m >> 2) & 3;
  const int s  = (m >> 4) & 7;
  const int cz = m >> 7;
  const int a0 = at * TILE;
  const int b0 = bt * TILE;
  const int bb = s >> 2;
  const int r  = s & 3;
  const int cbeg = cz * (N / FCSPL);
  const int cend = cbeg + (N / FCSPL);

  const int ta = tid & 15;
  const int tb = tid >> 4;
  const int* mrow = masks + bb * N;

  float rab[8][8];
#pragma unroll
  for (int x = 0; x < 8; ++x) {
    int ra = a0 + ((x >> 2) << 6) + ta * 4 + (x & 3);
    float ma = (mrow[ra] > 0) ? 1.0f : 0.0f;
#pragma unroll
    for (int y = 0; y < 8; ++y) {
      int cb = b0 + ((y >> 2) << 6) + tb * 4 + (y & 3);
      float mb = (mrow[cb] > 0) ? 1.0f : 0.0f;
      size_t idx = ((size_t)(bb * N + ra) * N + cb) * RNUM + r;
      rab[x][y] = sigmoidf_(logits[idx]) * ma * mb;
    }
  }

  float acc[8][2];
#pragma unroll
  for (int x = 0; x < 8; ++x) { acc[x][0] = 0.0f; acc[x][1] = 0.0f; }

  for (int c0 = cbeg; c0 < cend; c0 += FCT) {
    __syncthreads();
#pragma unroll
    for (int it = 0; it < 32; ++it) {
      int e = it * 256 + tid;
      int c = e & 63;
      int i = e >> 6;
      int pc = ((((i >> 2) ^ ((c >> 2) & 31)) & 31) << 2) | (i & 3);
      float mc = (mrow[c0 + c] > 0) ? 1.0f : 0.0f;
      {
        float mi = (mrow[a0 + i] > 0) ? 1.0f : 0.0f;
        size_t idx = ((size_t)(bb * N + a0 + i) * N + (c0 + c)) * RNUM + r;
        tA[c][pc] = sigmoidf_(logits[idx]) * mi * mc;
      }
      {
        float mi = (mrow[b0 + i] > 0) ? 1.0f : 0.0f;
        size_t idx = ((size_t)(bb * N + b0 + i) * N + (c0 + c)) * RNUM + r;
        tB[c][pc] = sigmoidf_(logits[idx]) * mi * mc;
      }
    }
    __syncthreads();

#pragma unroll 2
    for (int cg = 0; cg < FCT / 4; ++cg) {
      const float* pa = &tA[cg * 4][((ta ^ cg) & 31) << 2];
      const float* pb = &tB[cg * 4][((tb ^ cg) & 31) << 2];
#pragma unroll
      for (int dc = 0; dc < 4; ++dc) {
        float4 a0v = *(const float4*)(pa + dc * FSTR);
        float4 a1v = *(const float4*)(pa + dc * FSTR + 64);
        float4 b0v = *(const float4*)(pb + dc * FSTR);
        float4 b1v = *(const float4*)(pb + dc * FSTR + 64);
        float avv[8] = {a0v.x, a0v.y, a0v.z, a0v.w, a1v.x, a1v.y, a1v.z, a1v.w};
        float bvv[8] = {b0v.x, b0v.y, b0v.z, b0v.w, b1v.x, b1v.y, b1v.z, b1v.w};
#pragma unroll
        for (int x = 0; x < 8; ++x) {
#pragma unroll
          for (int y = 0; y < 4; ++y)
            acc[x][0] += fabsf(fmaf(-avv[x], bvv[y], rab[x][y]));
#pragma unroll
          for (int y = 4; y < 8; ++y)
            acc[x][1] += fabsf(fmaf(-avv[x], bvv[y], rab[x][y]));
        }
      }
    }
  }

  float tsum = 0.0f;
#pragma unroll
  for (int x = 0; x < 8; ++x) tsum += acc[x][0] + acc[x][1];
  for (int off = 32; off > 0; off >>= 1) tsum += __shfl_down(tsum, off, 64);
  const int wid = tid >> 6;
  if ((tid & 63) == 0) wsum[wid] = tsum;
  __syncthreads();
  if (tid == 0)
    atomicAdd(out, (wsum[0] + wsum[1] + wsum[2] + wsum[3]) * SCALE);
}

extern "C" void kernel_launch(void* const* d_in, const int* in_sizes, int n_in,
                              void* d_out, int out_size, void* d_ws, size_t ws_size,
                              hipStream_t stream) {
  const float* logits = (const float*)d_in[0];
  const int*   masks  = (const int*)d_in[1];
  float*       out    = (float*)d_out;

  const size_t P_BYTES = (size_t)NSLICE * N * N * sizeof(_Float16);  // 4 MB

  if (ws_size >= P_BYTES) {
    _Float16* P = (_Float16*)d_ws;
    prep_f16_kernel<<<(BNUM * N * N) / 256, 256, 0, stream>>>(logits, masks, P, out);
    const int nblocks = NCOLB + 4 * 4 * NSLICE * CSPLIT;  // 16 + 1024
    work_f16_kernel<<<nblocks, 256, 0, stream>>>(P, out);
  } else {
    zero_out_kernel<<<1, 1, 0, stream>>>(out);
    const int nblocks = NCOLB + 4 * 4 * NSLICE * FCSPL;   // 16 + 512
    work_f32_fallback<<<nblocks, 256, 0, stream>>>(logits, masks, out);
  }
}

// Round 11
// 117.416 us; speedup vs baseline: 1.0580x; 1.0580x over previous
//
#include <hip/hip_runtime.h>
#include <math.h>

#define N      512
#define RNUM   4
#define BNUM   2
#define NSLICE (RNUM * BNUM)
#define TILE   128               // (a,b) tile 128x128, 256 threads x (8x8)
#define CT     64                // full per-block c-range: ONE barrier
#define CSPLIT 8                 // 1024 main blocks
#define NCOLB  16                // colsum-role blocks (8 slices x 2 halves)
#define SCALE  0.0625f           // (1/2 relu-split) * (1/8 weight/(R*B))

typedef _Float16 half2_t __attribute__((ext_vector_type(2)));

__device__ __forceinline__ unsigned int h2u(half2_t h) {
  return __builtin_bit_cast(unsigned int, h);
}
__device__ __forceinline__ half2_t u2h(unsigned int u) {
  return __builtin_bit_cast(half2_t, u);
}

__device__ __forceinline__ float sigmoidf_(float x) {
  return __builtin_amdgcn_rcpf(1.0f + __expf(-x));   // f16-storage precision
}

__global__ void zero_out_kernel(float* out) { out[0] = 0.0f; }

// One thread per (b,i,j): reads float4 over r, writes 4 f16 slice planes
// P[s][i][j] (row-major, mask+sigmoid folded). Coalesced 2B stores.
__global__ __launch_bounds__(256) void prep_f16_kernel(const float* __restrict__ logits,
                                                       const int* __restrict__ masks,
                                                       _Float16* __restrict__ P,
                                                       float* __restrict__ out) {
  if (blockIdx.x == 0 && threadIdx.x == 0) out[0] = 0.0f;
  int t = blockIdx.x * 256 + threadIdx.x;      // 0 .. B*N*N-1
  int b = t >> 18;                              // / (N*N)
  int rem = t & (N * N - 1);
  int i = rem >> 9;
  int j = rem & (N - 1);
  float4 lg = *(const float4*)(logits + (size_t)t * 4);
  float mm = ((masks[b * N + i] > 0) && (masks[b * N + j] > 0)) ? 1.0f : 0.0f;
  size_t base = (size_t)b * RNUM * N * N + rem;
  P[base + 0 * (size_t)N * N] = (_Float16)(mm * sigmoidf_(lg.x));
  P[base + 1 * (size_t)N * N] = (_Float16)(mm * sigmoidf_(lg.y));
  P[base + 2 * (size_t)N * N] = (_Float16)(mm * sigmoidf_(lg.z));
  P[base + 3 * (size_t)N * N] = (_Float16)(mm * sigmoidf_(lg.w));
}

// Work kernel (f16, c-packed):
//  bid <  NCOLB : colsum role — Sum_c csum_c*(N-csum_c)  (factorized Sum(x))
//  bid >= NCOLB : main role — Sum |rab - a_c*b_c|, pairs packed along c:
//    t2 = v_pk_fma_f16(-av2, bv2, {rab,rab});  p2 = t2 & 0x7FFF7FFF;
//    acc2 = v_pk_add_f16(acc2, p2)             -> 3 ops / 2 elements.
// LDS: row-major tiles tA/tB [128 rows][64 c] f16 (NO transpose — P rows are
// contiguous in c). 8-c column blocks XOR-swizzled by key=(row>>2)&7:
//   elem (row,c) at block (c>>3)^key. Rows used by a thread differ by 4 ->
//   keys span all 8 -> b128 reads hit all 32 banks, 2 lanes/bank (free);
//   staging writes 2-way (free). Row stride 64 f16 = 128 B, no padding.
// R9 post-mortem: VALU-issue was flat vs R8 (~40 µs) — the stall was the LDS
// instruction stream (4x ds_read_b64/c + 16 ds_write_b16/chunk). This layout
// cuts LDS inst ~8x (16 b128 reads / 8 c's, 8 b128 writes / 64 c's) and
// removes the per-x broadcast (loop-invariant {rab,rab} in regs).
__global__ __launch_bounds__(256, 2) void work_f16_kernel(const _Float16* __restrict__ P,
                                                          float* __restrict__ out) {
  __shared__ __align__(16) _Float16 tA[128 * CT];
  __shared__ __align__(16) _Float16 tB[128 * CT];
  __shared__ float wsum[4];

  const int tid = threadIdx.x;
  const int bid = blockIdx.x;

  if (bid < NCOLB) {
    // ---- colsum role ----
    const int s    = bid >> 1;
    const int half = bid & 1;
    const int c    = half * 256 + tid;
    const _Float16* col = P + (size_t)s * N * N + c;
    float sum = 0.0f;
#pragma unroll 8
    for (int a = 0; a < N; ++a) sum += (float)col[(size_t)a * N];
    float v = sum * ((float)N - sum);
    for (int off = 32; off > 0; off >>= 1) v += __shfl_down(v, off, 64);
    const int wid = tid >> 6;
    if ((tid & 63) == 0) wsum[wid] = v;
    __syncthreads();
    if (tid == 0)
      atomicAdd(out, (wsum[0] + wsum[1] + wsum[2] + wsum[3]) * SCALE);
    return;
  }

  // ---- main role ----
  const int m  = bid - NCOLB;
  const int bt = m & 3;
  const int at = (m >> 2) & 3;
  const int s  = (m >> 4) & 7;
  const int cz = m >> 7;                    // 0..CSPLIT-1
  const int a0 = at * TILE;
  const int b0 = bt * TILE;
  const int c0 = cz * CT;                   // 64-wide c-range, one stage

  const int ta = tid & 15;
  const int tb = tid >> 4;

  const _Float16* Ph = P + (size_t)s * N * N;

  // loop-invariant broadcast pairs bc[x][y] = {rab, rab}
  half2_t bc[8][8];
#pragma unroll
  for (int x = 0; x < 8; ++x) {
    int ga = a0 + ((x >> 2) << 6) + (ta << 2) + (x & 3);
    const _Float16* rrow = Ph + (size_t)ga * N + b0;
    uint2 u0 = *(const uint2*)(rrow + (tb << 2));
    uint2 u1 = *(const uint2*)(rrow + 64 + (tb << 2));
    half2_t p0 = u2h(u0.x), p1 = u2h(u0.y), p2 = u2h(u1.x), p3 = u2h(u1.y);
    bc[x][0] = half2_t{p0.x, p0.x};
    bc[x][1] = half2_t{p0.y, p0.y};
    bc[x][2] = half2_t{p1.x, p1.x};
    bc[x][3] = half2_t{p1.y, p1.y};
    bc[x][4] = half2_t{p2.x, p2.x};
    bc[x][5] = half2_t{p2.y, p2.y};
    bc[x][6] = half2_t{p3.x, p3.x};
    bc[x][7] = half2_t{p3.y, p3.y};
  }

  // staging: thread copies one 128 B row-slice into swizzled LDS row
  {
    const int sx   = tid & 127;
    const int sarr = tid >> 7;              // 0 -> A, 1 -> B
    const _Float16* srow = Ph + (size_t)((sarr ? b0 : a0) + sx) * N + c0;
    _Float16* dst = (sarr ? tB : tA) + sx * CT;
    const int key = (sx >> 2) & 7;
    const uint4* src = (const uint4*)srow;
#pragma unroll
    for (int cbg = 0; cbg < 8; ++cbg) {
      uint4 q = src[cbg];
      *(uint4*)&dst[(cbg ^ key) << 3] = q;
    }
  }
  __syncthreads();

  half2_t acc2[8][2];
#pragma unroll
  for (int x = 0; x < 8; ++x) { acc2[x][0] = u2h(0u); acc2[x][1] = u2h(0u); }

  const int keyA = ta & 7;
  const int keyB = tb & 7;
  int arow[8], brow[8];
#pragma unroll
  for (int x = 0; x < 8; ++x)
    arow[x] = (((x >> 2) << 6) | (ta << 2) | (x & 3)) * CT;
#pragma unroll
  for (int y = 0; y < 8; ++y)
    brow[y] = (((y >> 2) << 6) | (tb << 2) | (y & 3)) * CT;

#pragma unroll 1
  for (int cb = 0; cb < 8; ++cb) {
    uint4 bq[8];
#pragma unroll
    for (int y = 0; y < 8; ++y)
      bq[y] = *(const uint4*)&tB[brow[y] + ((cb ^ keyB) << 3)];
#pragma unroll
    for (int x = 0; x < 8; ++x) {
      uint4 aq = *(const uint4*)&tA[arow[x] + ((cb ^ keyA) << 3)];
      unsigned int au[4] = {aq.x, aq.y, aq.z, aq.w};
#pragma unroll
      for (int y = 0; y < 8; ++y) {
        unsigned int bu[4] = {bq[y].x, bq[y].y, bq[y].z, bq[y].w};
#pragma unroll
        for (int k = 0; k < 4; ++k) {
          half2_t t2 = __builtin_elementwise_fma(-u2h(au[k]), u2h(bu[k]),
                                                 bc[x][y]);
          acc2[x][y & 1] += u2h(h2u(t2) & 0x7FFF7FFFu);
        }
      }
    }
  }

  float tsum = 0.0f;
#pragma unroll
  for (int x = 0; x < 8; ++x) {
    tsum += (float)acc2[x][0].x + (float)acc2[x][0].y +
            (float)acc2[x][1].x + (float)acc2[x][1].y;
  }

  for (int off = 32; off > 0; off >>= 1) tsum += __shfl_down(tsum, off, 64);

  const int wid = tid >> 6;
  if ((tid & 63) == 0) wsum[wid] = tsum;
  __syncthreads();
  if (tid == 0)
    atomicAdd(out, (wsum[0] + wsum[1] + wsum[2] + wsum[3]) * SCALE);
}

// ---------------- f32 fallback (no workspace) ----------------
#define FCT    64
#define FSTR   132
#define FCSPL  4

__global__ __launch_bounds__(256, 2) void work_f32_fallback(const float* __restrict__ logits,
                                                            const int* __restrict__ masks,
                                                            float* __restrict__ out) {
  __shared__ __align__(16) float tAf[FCT][FSTR];
  __shared__ __align__(16) float tBf[FCT][FSTR];
  __shared__ float wsum[4];

  const int tid = threadIdx.x;
  const int bid = blockIdx.x;

  if (bid < NCOLB) {
    const int s    = bid >> 1;
    const int half = bid & 1;
    const int c    = half * 256 + tid;
    const int bb   = s >> 2;
    const int r    = s & 3;
    const int* mrow = masks + bb * N;
    float mc = (mrow[c] > 0) ? 1.0f : 0.0f;
    float sum = 0.0f;
#pragma unroll 4
    for (int a = 0; a < N; ++a) {
      float ma = (mrow[a] > 0) ? 1.0f : 0.0f;
      size_t idx = ((size_t)(bb * N + a) * N + c) * RNUM + r;
      sum += sigmoidf_(logits[idx]) * ma * mc;
    }
    float v = sum * ((float)N - sum);
    for (int off = 32; off > 0; off >>= 1) v += __shfl_down(v, off, 64);
    const int wid = tid >> 6;
    if ((tid & 63) == 0) wsum[wid] = v;
    __syncthreads();
    if (tid == 0)
      atomicAdd(out, (wsum[0] + wsum[1] + wsum[2] + wsum[3]) * SCALE);
    return;
  }

  const int m  = bid - NCOLB;
  const int bt = m & 3;
  const int at = (m >> 2) & 3;
  const int s  = (m >> 4) & 7;
  const int cz = m >> 7;
  const int a0 = at * TILE;
  const int b0 = bt * TILE;
  const int bb = s >> 2;
  const int r  = s & 3;
  const int cbeg = cz * (N / FCSPL);
  const int cend = cbeg + (N / FCSPL);

  const int ta = tid & 15;
  const int tb = tid >> 4;
  const int* mrow = masks + bb * N;

  float rab[8][8];
#pragma unroll
  for (int x = 0; x < 8; ++x) {
    int ra = a0 + ((x >> 2) << 6) + ta * 4 + (x & 3);
    float ma = (mrow[ra] > 0) ? 1.0f : 0.0f;
#pragma unroll
    for (int y = 0; y < 8; ++y) {
      int cb = b0 + ((y >> 2) << 6) + tb * 4 + (y & 3);
      float mb = (mrow[cb] > 0) ? 1.0f : 0.0f;
      size_t idx = ((size_t)(bb * N + ra) * N + cb) * RNUM + r;
      rab[x][y] = sigmoidf_(logits[idx]) * ma * mb;
    }
  }

  float acc[8][2];
#pragma unroll
  for (int x = 0; x < 8; ++x) { acc[x][0] = 0.0f; acc[x][1] = 0.0f; }

  for (int c0 = cbeg; c0 < cend; c0 += FCT) {
    __syncthreads();
#pragma unroll
    for (int it = 0; it < 32; ++it) {
      int e = it * 256 + tid;
      int c = e & 63;
      int i = e >> 6;
      int pc = ((((i >> 2) ^ ((c >> 2) & 31)) & 31) << 2) | (i & 3);
      float mc = (mrow[c0 + c] > 0) ? 1.0f : 0.0f;
      {
        float mi = (mrow[a0 + i] > 0) ? 1.0f : 0.0f;
        size_t idx = ((size_t)(bb * N + a0 + i) * N + (c0 + c)) * RNUM + r;
        tAf[c][pc] = sigmoidf_(logits[idx]) * mi * mc;
      }
      {
        float mi = (mrow[b0 + i] > 0) ? 1.0f : 0.0f;
        size_t idx = ((size_t)(bb * N + b0 + i) * N + (c0 + c)) * RNUM + r;
        tBf[c][pc] = sigmoidf_(logits[idx]) * mi * mc;
      }
    }
    __syncthreads();

#pragma unroll 2
    for (int cg = 0; cg < FCT / 4; ++cg) {
      const float* pa = &tAf[cg * 4][((ta ^ cg) & 31) << 2];
      const float* pb = &tBf[cg * 4][((tb ^ cg) & 31) << 2];
#pragma unroll
      for (int dc = 0; dc < 4; ++dc) {
        float4 a0v = *(const float4*)(pa + dc * FSTR);
        float4 a1v = *(const float4*)(pa + dc * FSTR + 64);
        float4 b0v = *(const float4*)(pb + dc * FSTR);
        float4 b1v = *(const float4*)(pb + dc * FSTR + 64);
        float avv[8] = {a0v.x, a0v.y, a0v.z, a0v.w, a1v.x, a1v.y, a1v.z, a1v.w};
        float bvv[8] = {b0v.x, b0v.y, b0v.z, b0v.w, b1v.x, b1v.y, b1v.z, b1v.w};
#pragma unroll
        for (int x = 0; x < 8; ++x) {
#pragma unroll
          for (int y = 0; y < 4; ++y)
            acc[x][0] += fabsf(fmaf(-avv[x], bvv[y], rab[x][y]));
#pragma unroll
          for (int y = 4; y < 8; ++y)
            acc[x][1] += fabsf(fmaf(-avv[x], bvv[y], rab[x][y]));
        }
      }
    }
  }

  float tsum = 0.0f;
#pragma unroll
  for (int x = 0; x < 8; ++x) tsum += acc[x][0] + acc[x][1];
  for (int off = 32; off > 0; off >>= 1) tsum += __shfl_down(tsum, off, 64);
  const int wid = tid >> 6;
  if ((tid & 63) == 0) wsum[wid] = tsum;
  __syncthreads();
  if (tid == 0)
    atomicAdd(out, (wsum[0] + wsum[1] + wsum[2] + wsum[3]) * SCALE);
}

extern "C" void kernel_launch(void* const* d_in, const int* in_sizes, int n_in,
                              void* d_out, int out_size, void* d_ws, size_t ws_size,
                              hipStream_t stream) {
  const float* logits = (const float*)d_in[0];
  const int*   masks  = (const int*)d_in[1];
  float*       out    = (float*)d_out;

  const size_t P_BYTES = (size_t)NSLICE * N * N * sizeof(_Float16);  // 4 MB

  if (ws_size >= P_BYTES) {
    _Float16* P = (_Float16*)d_ws;
    prep_f16_kernel<<<(BNUM * N * N) / 256, 256, 0, stream>>>(logits, masks, P, out);
    const int nblocks = NCOLB + 4 * 4 * NSLICE * CSPLIT;  // 16 + 1024
    work_f16_kernel<<<nblocks, 256, 0, stream>>>(P, out);
  } else {
    zero_out_kernel<<<1, 1, 0, stream>>>(out);
    const int nblocks = NCOLB + 4 * 4 * NSLICE * FCSPL;   // 16 + 512
    work_f32_fallback<<<nblocks, 256, 0, stream>>>(logits, masks, out);
  }
}